// Round 3
// baseline (405.090 us; speedup 1.0000x reference)
//
#include <hip/hip_runtime.h>
#include <hip/hip_fp16.h>

#define XDIM 256
#define YDIM 256
#define ZDIM 32
#define NT 384
#define NA 180
#define AG 4                    // angles per block
#define SW 263                  // dwords per staged row (odd -> bank spread)
#define SROWS 70                // 3 pad + 64 data + 3 pad
#define SLICE_DW (SROWS * SW)   // 18410 dwords = 73640 B
#define SMEM_BYTES 73664        // rounded; psum (8 KB) aliases the slice

// Block: one z-PAIR x 4 angles x one y-HALF (2 strips of 64 rows), 1024 thr.
// 73.6 KB LDS -> 2 blocks/CU = 32 waves/CU (vs 16 before): the kernel was
// latency-bound (VALUBusy 55%, LDS ~33%, nothing saturated), so double the
// wave pool. Halves combine with atomicAdd into a memset-zeroed output.
// LDS cell (y,x) holds half2(vol[z0],vol[z1]); packed-f16 x-lerp, f32 y-lerp.
// Pad 3 + ceil'd interval starts keeps every executed tap inside the stage:
//   excursion past the volume <= 2|slope| (<3), bilinear +1, partition slop
//   <=1 row; strip-boundary t's use identical fp expressions in both
//   half-blocks -> exact partition (no gap / double count).
__global__ __launch_bounds__(1024, 8) void proj_kernel(
    const float* __restrict__ vol, const float* __restrict__ phis,
    float* __restrict__ out) {
  extern __shared__ char smem[];
  __half2* sl = reinterpret_cast<__half2*>(smem);
  float2* psum = reinterpret_cast<float2*>(smem);  // reused after compute

  const int tid = threadIdx.x;
  const int zp = blockIdx.x;  // 0..15 z-pair
  const int ag = blockIdx.y;  // 0..44 angle group
  const int h = blockIdx.z;   // 0..1 y-half (strips 2h, 2h+1)
  const int col = tid & 255;
  const int q = tid >> 8;     // t-quarter (it % 4 == q)
  const float u = (float)col - 127.5f;

  float c_[AG], s_[AG], bx_[AG], by_[AG];
  int glo_[AG], ghi_[AG];

#pragma unroll
  for (int j = 0; j < AG; ++j) {
    const float phi = phis[ag * AG + j] * 0.017453292519943295f;
    const float c = cosf(phi), s = sinf(phi);
    const float bx = fmaf(u, -s, 127.5f);
    const float by = fmaf(u, c, 127.5f);
    c_[j] = c; s_[j] = s; bx_[j] = bx; by_[j] = by;
    float lo = 0.f, hi = (float)NT;
    if (fabsf(c) < 1e-6f) {
      if (bx <= -1.f || bx >= 256.f) { lo = 1.f; hi = 0.f; }
    } else {
      float t1 = (-1.f - bx) / c + 191.5f;
      float t2 = (256.f - bx) / c + 191.5f;
      lo = fmaxf(lo, fminf(t1, t2) - 2.f);
      hi = fminf(hi, fmaxf(t1, t2) + 2.f);
    }
    if (fabsf(s) < 1e-6f) {
      if (by <= -1.f || by >= 256.f) { lo = 1.f; hi = 0.f; }
    } else {
      float t1 = (-1.f - by) / s + 191.5f;
      float t2 = (256.f - by) / s + 191.5f;
      lo = fmaxf(lo, fminf(t1, t2) - 2.f);
      hi = fminf(hi, fmaxf(t1, t2) + 2.f);
    }
    glo_[j] = (int)ceilf(fmaxf(lo, 0.f));  // ceil: keeps excursion <= 2|slope|
    ghi_[j] = (int)fminf(hi, (float)NT);   // trunc shrinks: safe
  }

  float2 acc[AG];
#pragma unroll
  for (int j = 0; j < AG; ++j) acc[j] = make_float2(0.f, 0.f);

  const float* vsrc0 = vol + (zp * 2) * (YDIM * XDIM);
  const float* vsrc1 = vsrc0 + YDIM * XDIM;

#pragma unroll
  for (int st2 = 0; st2 < 2; ++st2) {
    const int st = h * 2 + st2;
    const int gr0 = st * 64 - 3;  // global row of local row 0
    __syncthreads();              // prior strip's reads done before overwrite

    // ---- col pads: lx in {0,1,2} u {259..262}, all 70 rows (7*70=490 thr)
    if (tid < SROWS * 7) {
      int r = tid / 7;
      int cc = tid - r * 7;
      int lx = cc < 3 ? cc : cc + 256;
      sl[r * SW + lx] = __floats2half2_rn(0.f, 0.f);
    }
    // ---- fill 70 rows x 256 cols; out-of-volume rows write zeros (row pads)
    for (int i = 0; i < 18; ++i) {
      int k = tid + (i << 10);
      if (k < SROWS * 256) {
        int r = k >> 8;
        int x = k & 255;
        int gr = gr0 + r;
        __half2 v = __floats2half2_rn(0.f, 0.f);
        if ((unsigned)gr < 256u) {
          int gi = gr * XDIM + x;
          v = __floats2half2_rn(vsrc0[gi], vsrc1[gi]);
        }
        sl[r * SW + x + 3] = v;
      }
    }
    __syncthreads();

    // cell index: lr = y0 - gr0 = y0 + 3 - 64*st, lx = x0 + 3
    const int K = (3 - 64 * st) * SW + 3;
#pragma unroll
    for (int j = 0; j < AG; ++j) {
      const float c = c_[j], s = s_[j], bx = bx_[j], by = by_[j];
      const int glo = glo_[j], ghi = ghi_[j];
      int lo, hi;
      if (fabsf(s) < 1e-6f) {
        // horizontal ray: whole interval belongs to the strip containing by
        int stown = min(3, max(0, ((int)floorf(by)) >> 6));
        lo = (st == stown) ? glo : 0;
        hi = (st == stown) ? ghi : 0;
      } else {
        // identical expressions in adjacent strips/blocks -> exact partition
        float ta = ((float)(64 * st) - by) / s + 191.5f;
        float tb = ((float)(64 * st + 64) - by) / s + 191.5f;
        int ia = (int)ceilf(ta);
        int ib = (int)ceilf(tb);
        if (s > 0.f) {
          lo = (st == 0) ? glo : max(glo, ia);
          hi = (st == 3) ? ghi : min(ghi, ib);
        } else {
          lo = (st == 3) ? glo : max(glo, ib);
          hi = (st == 0) ? ghi : min(ghi, ia);
        }
      }
      const int start = lo + ((q - lo) & 3);
      float t = (float)start - 191.5f;  // half-integers: t += 4 exact in fp32
      const float tend = (float)hi - 191.5f;
      float a0 = acc[j].x, a1 = acc[j].y;
#pragma unroll 2
      for (; t < tend; t += 4.f) {
        float x = fmaf(t, c, bx);
        float y = fmaf(t, s, by);
        float x0f = floorf(x), y0f = floorf(y);
        float fx = x - x0f, fy = y - y0f;
        int ai = (int)fmaf(y0f, (float)SW, x0f) + K;  // exact: |.| < 2^24
        const __half2* p = sl + ai;
        __half2 d00 = p[0], d01 = p[1], d10 = p[SW], d11 = p[SW + 1];
        __half2 fx2 = __float2half2_rn(fx);
        __half2 hx0 = __hfma2(__hsub2(d01, d00), fx2, d00);  // x-lerp, both z
        __half2 hx1 = __hfma2(__hsub2(d11, d10), fx2, d10);
        float omfy = 1.f - fy;
        a0 = fmaf(__low2float(hx0), omfy, a0);
        a0 = fmaf(__low2float(hx1), fy, a0);
        a1 = fmaf(__high2float(hx0), omfy, a1);
        a1 = fmaf(__high2float(hx1), fy, a1);
      }
      acc[j].x = a0; acc[j].y = a1;
    }
  }

  // ---- reduce 4 t-quarters (psum aliases slice LDS) and combine y-halves
#pragma unroll
  for (int j = 0; j < AG; ++j) {
    __syncthreads();
    psum[tid] = acc[j];
    __syncthreads();
    if (tid < 256) {
      float2 pa = psum[col], pb = psum[256 + col], pc = psum[512 + col],
             pd = psum[768 + col];
      const int a = ag * AG + j;
      atomicAdd(&out[(a * ZDIM + zp * 2) * XDIM + col],
                pa.x + pb.x + pc.x + pd.x);
      atomicAdd(&out[(a * ZDIM + zp * 2 + 1) * XDIM + col],
                pa.y + pb.y + pc.y + pd.y);
    }
  }
}

extern "C" void kernel_launch(void* const* d_in, const int* in_sizes, int n_in,
                              void* d_out, int out_size, void* d_ws, size_t ws_size,
                              hipStream_t stream) {
  const float* vol = (const float*)d_in[0];
  const float* phis = (const float*)d_in[1];
  float* out = (float*)d_out;
  (void)hipFuncSetAttribute((const void*)proj_kernel,
                            hipFuncAttributeMaxDynamicSharedMemorySize,
                            SMEM_BYTES);
  // halves accumulate via atomics -> output must start zeroed
  (void)hipMemsetAsync(out, 0, out_size, stream);
  dim3 grid(ZDIM / 2, NA / AG, 2);
  proj_kernel<<<grid, 1024, SMEM_BYTES, stream>>>(vol, phis, out);
}